// Round 5
// baseline (67.119 us; speedup 1.0000x reference)
//
#include <hip/hip_runtime.h>
#include <stdint.h>

#define B_SZ 2048
#define F_SZ 24
#define E_SZ 128
#define P_SZ 276            // F*(F-1)/2
#define BT   128            // batch rows per block
#define NBB  (B_SZ / BT)    // 16
#define SEGLEN 6
#define NSEG 56             // sum over fp of ceil((23-fp)/6)
#define NWG  (NSEG * NBB)   // 896 = 8 * 112

#define XB_ELEMS (B_SZ * F_SZ * E_SZ)   // 6,291,456  (12.6 MB bf16)
#define KB_ELEMS (P_SZ * E_SZ * E_SZ)   // 4,521,984  ( 9.0 MB bf16)
#define WS_NEED  ((size_t)(XB_ELEMS + KB_ELEMS) * 2)

#define XPREP_BLKS (XB_ELEMS / 2048)    // 3072
#define KPREP_BLKS (KB_ELEMS / 2048)    // 2208

typedef __bf16 bf16x8 __attribute__((ext_vector_type(8)));
typedef __bf16 bf16x4 __attribute__((ext_vector_type(4)));
typedef float  f32x16 __attribute__((ext_vector_type(16)));

#define FENCE asm volatile("" ::: "memory")

// ---- fused prepack: x -> xb (bf16 cast); kern [d,P,e] f32 -> kb [P][d][e]
//      bf16, PRE-SWIZZLED (slot s of row d holds source slot s ^ (d&15)) so a
//      linear LDS copy yields the XOR-swizzled image.
__global__ __launch_bounds__(256) void prepack_all(
    const float* __restrict__ x, const float* __restrict__ kern,
    __bf16* __restrict__ xb, __bf16* __restrict__ kb)
{
    const int bid = blockIdx.x;
    if (bid < XPREP_BLKS) {
        size_t g = (size_t)bid * 256 + threadIdx.x;
        float4 v0 = *(const float4*)(x + g * 8);
        float4 v1 = *(const float4*)(x + g * 8 + 4);
        bf16x8 h;
        h[0] = (__bf16)v0.x; h[1] = (__bf16)v0.y; h[2] = (__bf16)v0.z; h[3] = (__bf16)v0.w;
        h[4] = (__bf16)v1.x; h[5] = (__bf16)v1.y; h[6] = (__bf16)v1.z; h[7] = (__bf16)v1.w;
        *(bf16x8*)(xb + g * 8) = h;
    } else {
        int g = (bid - XPREP_BLKS) * 256 + threadIdx.x;  // 16B-slot id
        int p = g >> 11;
        int r = g & 2047;
        int d = r >> 4, s = r & 15;
        const float* src = kern + ((size_t)d * P_SZ + p) * E_SZ + ((s ^ (d & 15)) << 3);
        float4 v0 = *(const float4*)src;
        float4 v1 = *(const float4*)(src + 4);
        bf16x8 h;
        h[0] = (__bf16)v0.x; h[1] = (__bf16)v0.y; h[2] = (__bf16)v0.z; h[3] = (__bf16)v0.w;
        h[4] = (__bf16)v1.x; h[5] = (__bf16)v1.y; h[6] = (__bf16)v1.z; h[7] = (__bf16)v1.w;
        *(bf16x8*)(kb + (size_t)g * 8) = h;
    }
}

// ---- main: block = (pair segment sharing fp, 128-row batch tile).
//      Xp staged once/segment; K double-buffered across chained pairs with
//      counted vmcnt (raw s_barrier only -- no __syncthreads drain).
__global__ __launch_bounds__(256) void opn_main(
    const __bf16* __restrict__ xb,    // [B, F, E] bf16
    const __bf16* __restrict__ kb,    // [P][E][E] bf16, pre-swizzled
    float* __restrict__ out)          // [B, P] f32
{
    __shared__ short sXp[BT * E_SZ];        // 32 KB, persistent per segment
    __shared__ short sK[2][E_SZ * E_SZ];    // 64 KB, dbuf across pairs
    __shared__ short sQ[BT * E_SZ];         // 32 KB, per pair

    const int tid  = threadIdx.x;
    const int w    = tid >> 6, lane = tid & 63;
    const int orig = blockIdx.x;
    // XCD (orig&7) owns 2 batch tiles (256 rows -> 1.5MB xb slice, L2-fits)
    // x all 56 segments; long segments dispatch first (good tail).
    const int x  = orig & 7, il = orig >> 3;    // il 0..111
    const int bb = x * 2 + (il & 1);
    const int seg = il >> 1;                    // 0..55
    const int b0 = bb * BT;

    // seg -> (fp, q0, len): per-fp chains split into segments of <= SEGLEN
    int s = seg, fp = 0;
    for (;;) {
        int L = F_SZ - 1 - fp, ns = (L + SEGLEN - 1) / SEGLEN;
        if (s < ns) break;
        s -= ns; ++fp;
    }
    const int Lrow = F_SZ - 1 - fp;
    const int q0   = s * SEGLEN;
    const int len  = (Lrow - q0 < SEGLEN) ? (Lrow - q0) : SEGLEN;
    const int fq0  = fp + 1 + q0;
    const int pBase = fp * 23 - (fp * (fp - 1)) / 2 + q0;   // p of first pair

    // ---- staging helpers (all coalesced global_load_lds, 16B/lane) ----
    auto stage_x = [&](short* dst, int f) {     // X tile gather, swizzled src
#pragma unroll
        for (int t = 0; t < 8; ++t) {
            const int base = (w * 8 + t) * 64;
            const int slot = base + lane;
            const int r = slot >> 4, s16 = slot & 15;
            const int ss = s16 ^ (r & 15);
            __builtin_amdgcn_global_load_lds(
                (const __attribute__((address_space(1))) void*)
                    (xb + ((size_t)(b0 + r) * F_SZ + f) * E_SZ + ss * 8),
                (__attribute__((address_space(3))) void*)(dst + base * 8),
                16, 0, 0);
        }
    };
    auto stage_k = [&](short* dst, int p) {     // linear copy of pre-swz K_p
        const __bf16* kp = kb + (size_t)p * (E_SZ * E_SZ);
#pragma unroll
        for (int t = 0; t < 8; ++t) {
            const int base = (w * 8 + t) * 64;
            __builtin_amdgcn_global_load_lds(
                (const __attribute__((address_space(1))) void*)(kp + (size_t)(base + lane) * 8),
                (__attribute__((address_space(3))) void*)(dst + base * 8),
                16, 0, 0);
        }
    };

    // prologue: Xp + first K (8+8 instrs/wave in flight)
    stage_x(sXp, fp);
    stage_k(sK[0], pBase);

    const int l31 = lane & 31, hi = lane >> 5;
    const int brow  = w * 32 + l31;       // this lane's batch column (local)
    const int sxrow = brow * E_SZ;
    float* outp = out + (size_t)(b0 + brow) * P_SZ;

    for (int j = 0; j < len; ++j) {
        const int pb = j & 1;
        // a: issue next K (parity buf) + this pair's Xq
        if (j + 1 < len) stage_k(sK[pb ^ 1], pBase + j + 1);
        stage_x(sQ, fq0 + j);
        // b: wait K_j (+Xp on first iter) complete; 16 newest stay in flight
        if (j + 1 < len) { asm volatile("s_waitcnt vmcnt(16)" ::: "memory"); }
        else             { asm volatile("s_waitcnt vmcnt(8)"  ::: "memory"); }
        __builtin_amdgcn_s_barrier();
        FENCE;

        // c1: T[d,b] = K_p[d,e] . Xp[b,e]^T -- wave owns ALL 128 d for its
        // 32 batch cols; 32x32x16 MFMA, frags from XOR-swizzled LDS.
        f32x16 acc[4];
#pragma unroll
        for (int mt = 0; mt < 4; ++mt)
#pragma unroll
            for (int q = 0; q < 16; ++q) acc[mt][q] = 0.f;

#pragma unroll
        for (int kk = 0; kk < 8; ++kk) {
            const int e8 = kk * 2 + hi;
            bf16x8 bfr = *(const bf16x8*)&sXp[sxrow + ((e8 ^ (brow & 15)) << 3)];
#pragma unroll
            for (int mt = 0; mt < 4; ++mt) {
                const int arow = mt * 32 + l31;
                bf16x8 afr = *(const bf16x8*)&sK[pb][arow * E_SZ + ((e8 ^ (arow & 15)) << 3)];
                acc[mt] = __builtin_amdgcn_mfma_f32_32x32x16_bf16(afr, bfr, acc[mt], 0, 0, 0);
            }
        }
        // c2: wait Xq_j staged (K_{j+1} stays in flight), cross-wave barrier
        if (j + 1 < len) { asm volatile("s_waitcnt vmcnt(8)" ::: "memory"); }
        else             { asm volatile("s_waitcnt vmcnt(0)" ::: "memory"); }
        __builtin_amdgcn_s_barrier();
        FENCE;

        // epilogue: s = sum_d T[d,b] * Xq[b,d], fully lane-local.
        // D layout: col = lane&31 (= b), row(d) = (reg&3)+8*(reg>>2)+4*hi
        float sacc = 0.f;
#pragma unroll
        for (int mt = 0; mt < 4; ++mt) {
#pragma unroll
            for (int q = 0; q < 4; ++q) {
                bf16x4 xq = *(const bf16x4*)
                    &sQ[sxrow + (((mt * 4 + q) ^ (brow & 15)) << 3) + hi * 4];
                sacc += acc[mt][q * 4 + 0] * (float)xq[0]
                      + acc[mt][q * 4 + 1] * (float)xq[1]
                      + acc[mt][q * 4 + 2] * (float)xq[2]
                      + acc[mt][q * 4 + 3] * (float)xq[3];
            }
        }
        sacc += __shfl_xor(sacc, 32);     // combine the two hi row-groups
        if (hi == 0) outp[pBase + j] = sacc;

        // c3: protect sQ + K parity buffer before next pair's issues
        __builtin_amdgcn_s_barrier();
        FENCE;
    }
}

// ---------------- fallback (round-2 kernel, used if ws too small) -----------
__global__ __launch_bounds__(512, 4) void opn_fallback(
    const float* __restrict__ x, const float* __restrict__ kern,
    float* __restrict__ out)
{
    __shared__ short sA[128 * E_SZ];
    __shared__ short sB[E_SZ * E_SZ];
    __shared__ float red[2][128];

    const int tid = threadIdx.x;
    const int orig = blockIdx.x;
    const int nwg2 = P_SZ * 16;
    const int wgid = (orig & 7) * (nwg2 / 8) + (orig >> 3);
    const int p  = wgid >> 4;
    const int bb = wgid & 15;
    const int b0 = bb * 128;

    int fp = 0, rem = p;
    while (rem >= F_SZ - 1 - fp) { rem -= F_SZ - 1 - fp; ++fp; }
    const int fq = fp + 1 + rem;

#pragma unroll
    for (int k = 0; k < 4; ++k) {
        int i = tid + k * 512;
        int r = i >> 4, s8 = i & 15;
        const float* src = x + ((size_t)(b0 + r) * F_SZ + fp) * E_SZ + s8 * 8;
        float4 v0 = *(const float4*)src;
        float4 v1 = *(const float4*)(src + 4);
        bf16x8 h;
        h[0] = (__bf16)v0.x; h[1] = (__bf16)v0.y; h[2] = (__bf16)v0.z; h[3] = (__bf16)v0.w;
        h[4] = (__bf16)v1.x; h[5] = (__bf16)v1.y; h[6] = (__bf16)v1.z; h[7] = (__bf16)v1.w;
        *(bf16x8*)&sA[r * E_SZ + ((s8 ^ (r & 15)) << 3)] = h;
    }
#pragma unroll
    for (int k = 0; k < 4; ++k) {
        int i = tid + k * 512;
        int r = i >> 4, s8 = i & 15;
        const float* src = kern + ((size_t)r * P_SZ + p) * E_SZ + s8 * 8;
        float4 v0 = *(const float4*)src;
        float4 v1 = *(const float4*)(src + 4);
        bf16x8 h;
        h[0] = (__bf16)v0.x; h[1] = (__bf16)v0.y; h[2] = (__bf16)v0.z; h[3] = (__bf16)v0.w;
        h[4] = (__bf16)v1.x; h[5] = (__bf16)v1.y; h[6] = (__bf16)v1.z; h[7] = (__bf16)v1.w;
        *(bf16x8*)&sB[r * E_SZ + ((s8 ^ (r & 15)) << 3)] = h;
    }
    __syncthreads();

    const int w = tid >> 6, lane = tid & 63;
    const int l31 = lane & 31, hi = lane >> 5;
    const int mh = w >> 2, ng = w & 3;

    f32x16 acc[2];
#pragma unroll
    for (int mt = 0; mt < 2; ++mt)
#pragma unroll
        for (int j = 0; j < 16; ++j) acc[mt][j] = 0.f;

    const int brow = ng * 32 + l31;
#pragma unroll
    for (int kk = 0; kk < 8; ++kk) {
        const int e8 = kk * 2 + hi;
        bf16x8 bfr = *(const bf16x8*)&sA[brow * E_SZ + ((e8 ^ (brow & 15)) << 3)];
#pragma unroll
        for (int mt = 0; mt < 2; ++mt) {
            int arow = (mh * 2 + mt) * 32 + l31;
            bf16x8 afr = *(const bf16x8*)&sB[arow * E_SZ + ((e8 ^ (arow & 15)) << 3)];
            acc[mt] = __builtin_amdgcn_mfma_f32_32x32x16_bf16(afr, bfr, acc[mt], 0, 0, 0);
        }
    }

    const float* xqp = x + ((size_t)(b0 + brow) * F_SZ + fq) * E_SZ;
    float sv = 0.f;
#pragma unroll
    for (int mt = 0; mt < 2; ++mt) {
        const int dbase = (mh * 2 + mt) * 32 + hi * 4;
#pragma unroll
        for (int q = 0; q < 4; ++q) {
            float4 xq = *(const float4*)(xqp + dbase + q * 8);
            sv += acc[mt][q * 4 + 0] * xq.x + acc[mt][q * 4 + 1] * xq.y
                + acc[mt][q * 4 + 2] * xq.z + acc[mt][q * 4 + 3] * xq.w;
        }
    }
    sv += __shfl_xor(sv, 32);
    if (hi == 0) red[mh][brow] = sv;
    __syncthreads();

    if (tid < 128)
        out[(size_t)(b0 + tid) * P_SZ + p] = red[0][tid] + red[1][tid];
}

extern "C" void kernel_launch(void* const* d_in, const int* in_sizes, int n_in,
                              void* d_out, int out_size, void* d_ws, size_t ws_size,
                              hipStream_t stream) {
    const float* x    = (const float*)d_in[0];   // [2048, 24, 128] f32
    const float* kern = (const float*)d_in[1];   // [128, 276, 128] f32
    float* out = (float*)d_out;                  // [2048, 276] f32

    if (ws_size >= WS_NEED) {
        __bf16* xb = (__bf16*)d_ws;
        __bf16* kb = xb + XB_ELEMS;
        prepack_all<<<dim3(XPREP_BLKS + KPREP_BLKS), 256, 0, stream>>>(x, kern, xb, kb);
        opn_main<<<dim3(NWG), 256, 0, stream>>>(xb, kb, out);
    } else {
        opn_fallback<<<dim3(P_SZ * 16), 512, 0, stream>>>(x, kern, out);
    }
}

// Round 6
// 47.368 us; speedup vs baseline: 1.4170x; 1.4170x over previous
//
#include <hip/hip_runtime.h>
#include <stdint.h>

#define B_SZ 2048
#define F_SZ 24
#define E_SZ 128
#define P_SZ 276            // F*(F-1)/2
#define BT   128            // batch rows per block
#define NBB  (B_SZ / BT)    // 16
#define SEGLEN 4
#define NSEG 78             // sum over fp of ceil((23-fp)/4)
#define NWG  (NSEG * NBB)   // 1248 = 8 * 156

#define XB_ELEMS (B_SZ * F_SZ * E_SZ)   // 6,291,456  (12.6 MB bf16)
#define KB_ELEMS (P_SZ * E_SZ * E_SZ)   // 4,521,984  ( 9.0 MB bf16)
#define WS_NEED  ((size_t)(XB_ELEMS + KB_ELEMS) * 2)

#define XPREP_BLKS (XB_ELEMS / 2048)    // 3072
#define KPREP_BLKS (KB_ELEMS / 2048)    // 2208

typedef __bf16 bf16x8 __attribute__((ext_vector_type(8)));
typedef __bf16 bf16x4 __attribute__((ext_vector_type(4)));
typedef float  f32x16 __attribute__((ext_vector_type(16)));

// ---- fused prepack: x -> xb (bf16 cast); kern [d,P,e] f32 -> kb [P][d][e]
//      bf16, PRE-SWIZZLED (slot s of row d holds source slot s ^ (d&15)) so a
//      linear LDS copy yields the XOR-swizzled image.
__global__ __launch_bounds__(256) void prepack_all(
    const float* __restrict__ x, const float* __restrict__ kern,
    __bf16* __restrict__ xb, __bf16* __restrict__ kb)
{
    const int bid = blockIdx.x;
    if (bid < XPREP_BLKS) {
        size_t g = (size_t)bid * 256 + threadIdx.x;
        float4 v0 = *(const float4*)(x + g * 8);
        float4 v1 = *(const float4*)(x + g * 8 + 4);
        bf16x8 h;
        h[0] = (__bf16)v0.x; h[1] = (__bf16)v0.y; h[2] = (__bf16)v0.z; h[3] = (__bf16)v0.w;
        h[4] = (__bf16)v1.x; h[5] = (__bf16)v1.y; h[6] = (__bf16)v1.z; h[7] = (__bf16)v1.w;
        *(bf16x8*)(xb + g * 8) = h;
    } else {
        int g = (bid - XPREP_BLKS) * 256 + threadIdx.x;  // 16B-slot id
        int p = g >> 11;
        int r = g & 2047;
        int d = r >> 4, s = r & 15;
        const float* src = kern + ((size_t)d * P_SZ + p) * E_SZ + ((s ^ (d & 15)) << 3);
        float4 v0 = *(const float4*)src;
        float4 v1 = *(const float4*)(src + 4);
        bf16x8 h;
        h[0] = (__bf16)v0.x; h[1] = (__bf16)v0.y; h[2] = (__bf16)v0.z; h[3] = (__bf16)v0.w;
        h[4] = (__bf16)v1.x; h[5] = (__bf16)v1.y; h[6] = (__bf16)v1.z; h[7] = (__bf16)v1.w;
        *(bf16x8*)(kb + (size_t)g * 8) = h;
    }
}

// ---- main: block = (pair segment sharing fp, 128-row batch tile).
//      Xp staged once per segment then held in regs as MFMA B-fragments;
//      one 32KB X buffer reused for each pair's Xq; K staged per pair with
//      next-K issue overlapped with the epilogue. 64KB LDS -> 2 blocks/CU.
__global__ __launch_bounds__(256, 2) void opn_main(
    const __bf16* __restrict__ xb,    // [B, F, E] bf16
    const __bf16* __restrict__ kb,    // [P][E][E] bf16, pre-swizzled
    float* __restrict__ out)          // [B, P] f32
{
    __shared__ short sK[E_SZ * E_SZ];   // 32 KB swizzled K_p
    __shared__ short sX[BT * E_SZ];     // 32 KB swizzled Xp (then Xq per pair)

    const int tid  = threadIdx.x;
    const int w    = tid >> 6, lane = tid & 63;
    const int orig = blockIdx.x;
    // XCD (orig&7) owns 2 batch tiles (256 rows -> 1.6MB xb slice, L2-fits)
    // x all 78 segments; its 2 same-seg blocks run adjacent (K_p L2-shared).
    const int xcd = orig & 7, il = orig >> 3;   // il 0..155
    const int bb  = xcd * 2 + (il & 1);
    const int seg = il >> 1;                    // 0..77
    const int b0  = bb * BT;

    // seg -> (fp, q0, len): per-fp pair chains split into segments of <= 4
    int s = seg, fp = 0;
    for (;;) {
        int L = F_SZ - 1 - fp, ns = (L + SEGLEN - 1) / SEGLEN;
        if (s < ns) break;
        s -= ns; ++fp;
    }
    const int Lrow  = F_SZ - 1 - fp;
    const int q0    = s * SEGLEN;
    const int len   = (Lrow - q0 < SEGLEN) ? (Lrow - q0) : SEGLEN;
    const int fq0   = fp + 1 + q0;
    const int pBase = fp * 23 - (fp * (fp - 1)) / 2 + q0;

    // ---- staging helpers (coalesced global_load_lds, 16B/lane) ----
    auto stage_x = [&](int f) {          // X tile gather, swizzle in src addr
#pragma unroll
        for (int t = 0; t < 8; ++t) {
            const int base = (w * 8 + t) * 64;
            const int slot = base + lane;
            const int r = slot >> 4, s16 = slot & 15;
            const int ss = s16 ^ (r & 15);
            __builtin_amdgcn_global_load_lds(
                (const __attribute__((address_space(1))) void*)
                    (xb + ((size_t)(b0 + r) * F_SZ + f) * E_SZ + ss * 8),
                (__attribute__((address_space(3))) void*)(sX + base * 8),
                16, 0, 0);
        }
    };
    auto stage_k = [&](int p) {          // linear copy of pre-swizzled K_p
        const __bf16* kp = kb + (size_t)p * (E_SZ * E_SZ);
#pragma unroll
        for (int t = 0; t < 8; ++t) {
            const int base = (w * 8 + t) * 64;
            __builtin_amdgcn_global_load_lds(
                (const __attribute__((address_space(1))) void*)(kp + (size_t)(base + lane) * 8),
                (__attribute__((address_space(3))) void*)(sK + base * 8),
                16, 0, 0);
        }
    };

    const int l31 = lane & 31, hi = lane >> 5;
    const int brow  = w * 32 + l31;      // this lane's batch column (local)
    const int sxrow = brow * E_SZ;
    const int bsw   = (brow & 15);
    float* outp = out + (size_t)(b0 + brow) * P_SZ;

    // ---- prologue: stage Xp, pull B-fragments into registers (reused for
    //      the whole segment), then free sX for Xq use. ----
    stage_x(fp);
    asm volatile("s_waitcnt vmcnt(0)" ::: "memory");
    __builtin_amdgcn_sched_barrier(0);
    __builtin_amdgcn_s_barrier();

    bf16x8 xpf[8];
#pragma unroll
    for (int kk = 0; kk < 8; ++kk) {
        const int e8 = kk * 2 + hi;
        xpf[kk] = *(const bf16x8*)&sX[sxrow + ((e8 ^ bsw) << 3)];
    }
    asm volatile("s_waitcnt lgkmcnt(0)" ::: "memory");
    __builtin_amdgcn_sched_barrier(0);
    __builtin_amdgcn_s_barrier();        // all waves done reading sX

    stage_k(pBase);                      // first K in flight

    for (int j = 0; j < len; ++j) {
        // issue this pair's Xq into sX (K_j already in flight: 8+8 outstanding)
        stage_x(fq0 + j);
        asm volatile("s_waitcnt vmcnt(8)" ::: "memory");   // my K_j done
        __builtin_amdgcn_sched_barrier(0);
        __builtin_amdgcn_s_barrier();                      // K_j fully staged

        // T[d,b] = K_p[d,e] . Xp[b,e]^T -- wave owns all 128 d for its 32 b.
        f32x16 acc[4];
#pragma unroll
        for (int mt = 0; mt < 4; ++mt)
#pragma unroll
            for (int q = 0; q < 16; ++q) acc[mt][q] = 0.f;

#pragma unroll
        for (int kk = 0; kk < 8; ++kk) {
            const int e8 = kk * 2 + hi;
#pragma unroll
            for (int mt = 0; mt < 4; ++mt) {
                const int arow = mt * 32 + l31;
                bf16x8 afr = *(const bf16x8*)&sK[arow * E_SZ + ((e8 ^ (arow & 15)) << 3)];
                acc[mt] = __builtin_amdgcn_mfma_f32_32x32x16_bf16(afr, xpf[kk], acc[mt], 0, 0, 0);
            }
        }

        asm volatile("s_waitcnt vmcnt(0)" ::: "memory");   // Xq_j staged
        __builtin_amdgcn_sched_barrier(0);
        __builtin_amdgcn_s_barrier();                      // all MFMA done too

        // prefetch next K during the epilogue (sK is free now)
        if (j + 1 < len) stage_k(pBase + j + 1);

        // epilogue: s = sum_d T[d,b] * Xq[b,d], lane-local.
        // D layout: col = lane&31 (= b), row(d) = (reg&3)+8*(reg>>2)+4*hi
        float sacc = 0.f;
#pragma unroll
        for (int mt = 0; mt < 4; ++mt) {
#pragma unroll
            for (int q = 0; q < 4; ++q) {
                bf16x4 xq = *(const bf16x4*)
                    &sX[sxrow + (((mt * 4 + q) ^ bsw) << 3) + hi * 4];
                sacc += acc[mt][q * 4 + 0] * (float)xq[0]
                      + acc[mt][q * 4 + 1] * (float)xq[1]
                      + acc[mt][q * 4 + 2] * (float)xq[2]
                      + acc[mt][q * 4 + 3] * (float)xq[3];
            }
        }
        sacc += __shfl_xor(sacc, 32);    // combine the two hi row-groups
        if (hi == 0) outp[pBase + j] = sacc;

        __builtin_amdgcn_s_barrier();    // sX free before next pair's Xq
    }
}

// ---------------- fallback (round-2 kernel, used if ws too small) -----------
__global__ __launch_bounds__(512, 4) void opn_fallback(
    const float* __restrict__ x, const float* __restrict__ kern,
    float* __restrict__ out)
{
    __shared__ short sA[128 * E_SZ];
    __shared__ short sB[E_SZ * E_SZ];
    __shared__ float red[2][128];

    const int tid = threadIdx.x;
    const int orig = blockIdx.x;
    const int nwg2 = P_SZ * 16;
    const int wgid = (orig & 7) * (nwg2 / 8) + (orig >> 3);
    const int p  = wgid >> 4;
    const int bb = wgid & 15;
    const int b0 = bb * 128;

    int fp = 0, rem = p;
    while (rem >= F_SZ - 1 - fp) { rem -= F_SZ - 1 - fp; ++fp; }
    const int fq = fp + 1 + rem;

#pragma unroll
    for (int k = 0; k < 4; ++k) {
        int i = tid + k * 512;
        int r = i >> 4, s8 = i & 15;
        const float* src = x + ((size_t)(b0 + r) * F_SZ + fp) * E_SZ + s8 * 8;
        float4 v0 = *(const float4*)src;
        float4 v1 = *(const float4*)(src + 4);
        bf16x8 h;
        h[0] = (__bf16)v0.x; h[1] = (__bf16)v0.y; h[2] = (__bf16)v0.z; h[3] = (__bf16)v0.w;
        h[4] = (__bf16)v1.x; h[5] = (__bf16)v1.y; h[6] = (__bf16)v1.z; h[7] = (__bf16)v1.w;
        *(bf16x8*)&sA[r * E_SZ + ((s8 ^ (r & 15)) << 3)] = h;
    }
#pragma unroll
    for (int k = 0; k < 4; ++k) {
        int i = tid + k * 512;
        int r = i >> 4, s8 = i & 15;
        const float* src = kern + ((size_t)r * P_SZ + p) * E_SZ + s8 * 8;
        float4 v0 = *(const float4*)src;
        float4 v1 = *(const float4*)(src + 4);
        bf16x8 h;
        h[0] = (__bf16)v0.x; h[1] = (__bf16)v0.y; h[2] = (__bf16)v0.z; h[3] = (__bf16)v0.w;
        h[4] = (__bf16)v1.x; h[5] = (__bf16)v1.y; h[6] = (__bf16)v1.z; h[7] = (__bf16)v1.w;
        *(bf16x8*)&sB[r * E_SZ + ((s8 ^ (r & 15)) << 3)] = h;
    }
    __syncthreads();

    const int w = tid >> 6, lane = tid & 63;
    const int l31 = lane & 31, hi = lane >> 5;
    const int mh = w >> 2, ng = w & 3;

    f32x16 acc[2];
#pragma unroll
    for (int mt = 0; mt < 2; ++mt)
#pragma unroll
        for (int j = 0; j < 16; ++j) acc[mt][j] = 0.f;

    const int brow = ng * 32 + l31;
#pragma unroll
    for (int kk = 0; kk < 8; ++kk) {
        const int e8 = kk * 2 + hi;
        bf16x8 bfr = *(const bf16x8*)&sA[brow * E_SZ + ((e8 ^ (brow & 15)) << 3)];
#pragma unroll
        for (int mt = 0; mt < 2; ++mt) {
            int arow = (mh * 2 + mt) * 32 + l31;
            bf16x8 afr = *(const bf16x8*)&sB[arow * E_SZ + ((e8 ^ (arow & 15)) << 3)];
            acc[mt] = __builtin_amdgcn_mfma_f32_32x32x16_bf16(afr, bfr, acc[mt], 0, 0, 0);
        }
    }

    const float* xqp = x + ((size_t)(b0 + brow) * F_SZ + fq) * E_SZ;
    float sv = 0.f;
#pragma unroll
    for (int mt = 0; mt < 2; ++mt) {
        const int dbase = (mh * 2 + mt) * 32 + hi * 4;
#pragma unroll
        for (int q = 0; q < 4; ++q) {
            float4 xq = *(const float4*)(xqp + dbase + q * 8);
            sv += acc[mt][q * 4 + 0] * xq.x + acc[mt][q * 4 + 1] * xq.y
                + acc[mt][q * 4 + 2] * xq.z + acc[mt][q * 4 + 3] * xq.w;
        }
    }
    sv += __shfl_xor(sv, 32);
    if (hi == 0) red[mh][brow] = sv;
    __syncthreads();

    if (tid < 128)
        out[(size_t)(b0 + tid) * P_SZ + p] = red[0][tid] + red[1][tid];
}

extern "C" void kernel_launch(void* const* d_in, const int* in_sizes, int n_in,
                              void* d_out, int out_size, void* d_ws, size_t ws_size,
                              hipStream_t stream) {
    const float* x    = (const float*)d_in[0];   // [2048, 24, 128] f32
    const float* kern = (const float*)d_in[1];   // [128, 276, 128] f32
    float* out = (float*)d_out;                  // [2048, 276] f32

    if (ws_size >= WS_NEED) {
        __bf16* xb = (__bf16*)d_ws;
        __bf16* kb = xb + XB_ELEMS;
        prepack_all<<<dim3(XPREP_BLKS + KPREP_BLKS), 256, 0, stream>>>(x, kern, xb, kb);
        opn_main<<<dim3(NWG), 256, 0, stream>>>(xb, kb, out);
    } else {
        opn_fallback<<<dim3(P_SZ * 16), 512, 0, stream>>>(x, kern, out);
    }
}

// Round 7
// 46.492 us; speedup vs baseline: 1.4437x; 1.0188x over previous
//
#include <hip/hip_runtime.h>
#include <stdint.h>

#define B_SZ 2048
#define F_SZ 24
#define E_SZ 128
#define P_SZ 276            // F*(F-1)/2
#define BT   128            // batch rows per block
#define NWG  (P_SZ * 16)    // 4416 = 8 * 552 (clean XCD split)

#define XT_ELEMS (B_SZ * F_SZ * E_SZ)   // 6,291,456 per x-transform (12.6 MB)
#define KB_ELEMS (P_SZ * E_SZ * E_SZ)   // 4,521,984 (9.0 MB)
#define WS_NEED  ((size_t)(2 * XT_ELEMS + KB_ELEMS) * 2)   // 34.2 MB

#define XPREP_BLKS (F_SZ * 64)          // 1536  (one per (f, 32-row group))
#define KPREP_BLKS (KB_ELEMS / 2048)    // 2208

typedef __bf16 bf16x8 __attribute__((ext_vector_type(8)));
typedef __bf16 bf16x4 __attribute__((ext_vector_type(4)));
typedef float  f32x16 __attribute__((ext_vector_type(16)));

// ---- prepack ----------------------------------------------------------------
// xft[f][grp<64][kk<8][lane<64][8]: lane=(hi*32+l31) holds
//   x[grp*32+l31][f][kk*16+hi*8+i]  -> MFMA B-frag loads are 1KB coalesced.
// xqt[f][grp<64][dq<32][bl<32][4]:  x[grp*32+bl][f][dq*4+i]
//   -> epilogue Xq loads are 2x256B coalesced dwordx2.
// kb[p][d][slot]: pre-XOR-swizzled K so a linear LDS DMA lands swizzled.
__global__ __launch_bounds__(256) void prepack_all(
    const float* __restrict__ x, const float* __restrict__ kern,
    __bf16* __restrict__ xft, __bf16* __restrict__ xqt, __bf16* __restrict__ kb)
{
    const int bid = blockIdx.x;
    const int tid = threadIdx.x;
    if (bid < XPREP_BLKS) {
        const int f = bid >> 6, grp = bid & 63;
        __shared__ float sT[32][129];       // +1 pad: conflict-free col reads
        {
            const int row = tid >> 3, c0 = (tid & 7) * 16;
            const float* src = x + ((size_t)(grp * 32 + row) * F_SZ + f) * E_SZ + c0;
            float4 v0 = ((const float4*)src)[0];
            float4 v1 = ((const float4*)src)[1];
            float4 v2 = ((const float4*)src)[2];
            float4 v3 = ((const float4*)src)[3];
            *(float4*)&sT[row][c0]      = v0;
            *(float4*)&sT[row][c0 + 4]  = v1;
            *(float4*)&sT[row][c0 + 8]  = v2;
            *(float4*)&sT[row][c0 + 12] = v3;
        }
        __syncthreads();
        {
            __bf16* dst = xft + ((size_t)(f * 64 + grp) * 8) * 512;
#pragma unroll
            for (int u = 0; u < 2; ++u) {
                const int slot = tid * 2 + u;
                const int kk = slot >> 6, lane = slot & 63;
                const int l31 = lane & 31, hi = lane >> 5;
                bf16x8 h;
#pragma unroll
                for (int i = 0; i < 8; ++i)
                    h[i] = (__bf16)sT[l31][kk * 16 + hi * 8 + i];
                *(bf16x8*)(dst + slot * 8) = h;
            }
        }
        {
            __bf16* dst = xqt + ((size_t)(f * 64 + grp) * 32) * 128;
#pragma unroll
            for (int u = 0; u < 4; ++u) {
                const int slot = tid * 4 + u;
                const int dq = slot >> 5, bl = slot & 31;
                bf16x4 h;
#pragma unroll
                for (int i = 0; i < 4; ++i)
                    h[i] = (__bf16)sT[bl][dq * 4 + i];
                *(bf16x4*)(dst + slot * 4) = h;
            }
        }
    } else {
        int g = (bid - XPREP_BLKS) * 256 + tid;   // 16B-slot id
        int p = g >> 11, r = g & 2047;
        int d = r >> 4, s = r & 15;
        const float* src = kern + ((size_t)d * P_SZ + p) * E_SZ + ((s ^ (d & 15)) << 3);
        float4 v0 = *(const float4*)src;
        float4 v1 = *(const float4*)(src + 4);
        bf16x8 h;
        h[0] = (__bf16)v0.x; h[1] = (__bf16)v0.y; h[2] = (__bf16)v0.z; h[3] = (__bf16)v0.w;
        h[4] = (__bf16)v1.x; h[5] = (__bf16)v1.y; h[6] = (__bf16)v1.z; h[7] = (__bf16)v1.w;
        *(bf16x8*)(kb + (size_t)g * 8) = h;
    }
}

// ---- main: one block = (pair p, 128-row batch tile). K_p is the ONLY
//      LDS/DMA traffic; Xp fragments and Xq values load coalesced into regs.
__global__ __launch_bounds__(256) void opn_main(
    const __bf16* __restrict__ xft, const __bf16* __restrict__ xqt,
    const __bf16* __restrict__ kb,  float* __restrict__ out)
{
    __shared__ short sK[E_SZ * E_SZ];   // 32 KB swizzled K_p

    const int tid = threadIdx.x, w = tid >> 6, lane = tid & 63;
    const int l31 = lane & 31, hi = lane >> 5;
    const int orig = blockIdx.x;
    // XCD (orig&7) owns 2 batch tiles x all pairs; pairs-major so the two
    // same-pair blocks on an XCD hit L2 on K_p; x slices (~3.2MB) L2-resident.
    const int xcd = orig & 7, il = orig >> 3;   // il 0..551
    const int p   = il >> 1;
    const int bb  = xcd * 2 + (il & 1);

    int fp = 0, rem = p;
    while (rem >= F_SZ - 1 - fp) { rem -= F_SZ - 1 - fp; ++fp; }
    const int fq = fp + 1 + rem;

    // K_p DMA: linear copy of pre-swizzled image (8 x 1KB per wave)
    const __bf16* kp = kb + (size_t)p * (E_SZ * E_SZ);
#pragma unroll
    for (int t = 0; t < 8; ++t) {
        const int base = (w * 8 + t) * 64;
        __builtin_amdgcn_global_load_lds(
            (const __attribute__((address_space(1))) void*)(kp + (size_t)(base + lane) * 8),
            (__attribute__((address_space(3))) void*)(&sK[base * 8]),
            16, 0, 0);
    }

    const int grp = bb * 4 + w;         // this wave's 32-row batch group
    // Xp MFMA B-fragments: 8 coalesced dwordx4 into regs
    bf16x8 xpf[8];
    const __bf16* xpb = xft + ((size_t)(fp * 64 + grp) * 8) * 512 + lane * 8;
#pragma unroll
    for (int kk = 0; kk < 8; ++kk)
        xpf[kk] = *(const bf16x8*)(xpb + kk * 512);
    // Xq: 16 coalesced dwordx2 into regs; lane (l31,hi) gets
    //   Xq[b=grp*32+l31][d = mt*32 + q*8 + hi*4 + i]
    bf16x4 xqr[4][4];
    const __bf16* xqb = xqt + ((size_t)(fq * 64 + grp) * 32) * 128 + hi * 128 + l31 * 4;
#pragma unroll
    for (int mt = 0; mt < 4; ++mt)
#pragma unroll
        for (int q = 0; q < 4; ++q)
            xqr[mt][q] = *(const bf16x4*)(xqb + (size_t)(mt * 8 + q * 2) * 128);

    __syncthreads();                    // drains K DMA + joins waves

    // T[d,b] = K_p[d,e] . Xp[b,e]^T; wave owns all 128 d for its 32 b-cols
    f32x16 acc[4];
#pragma unroll
    for (int mt = 0; mt < 4; ++mt)
#pragma unroll
        for (int q = 0; q < 16; ++q) acc[mt][q] = 0.f;

#pragma unroll
    for (int kk = 0; kk < 8; ++kk) {
        const int e8 = kk * 2 + hi;
#pragma unroll
        for (int mt = 0; mt < 4; ++mt) {
            const int arow = mt * 32 + l31;
            bf16x8 afr = *(const bf16x8*)&sK[arow * E_SZ + ((e8 ^ (arow & 15)) << 3)];
            acc[mt] = __builtin_amdgcn_mfma_f32_32x32x16_bf16(afr, xpf[kk], acc[mt], 0, 0, 0);
        }
    }

    // epilogue: s = sum_d T[d,b] * Xq[b,d] -- all lane-local registers.
    // D layout: col = lane&31 (= b), row(d) = (reg&3) + 8*(reg>>2) + 4*hi
    float s = 0.f;
#pragma unroll
    for (int mt = 0; mt < 4; ++mt)
#pragma unroll
        for (int q = 0; q < 4; ++q)
            s += acc[mt][q * 4 + 0] * (float)xqr[mt][q][0]
               + acc[mt][q * 4 + 1] * (float)xqr[mt][q][1]
               + acc[mt][q * 4 + 2] * (float)xqr[mt][q][2]
               + acc[mt][q * 4 + 3] * (float)xqr[mt][q][3];
    s += __shfl_xor(s, 32);             // combine the two hi row-groups
    if (hi == 0)
        out[(size_t)(bb * BT + w * 32 + l31) * P_SZ + p] = s;
}

// ---------------- fallback (round-2 kernel, used if ws too small) -----------
__global__ __launch_bounds__(512, 4) void opn_fallback(
    const float* __restrict__ x, const float* __restrict__ kern,
    float* __restrict__ out)
{
    __shared__ short sA[128 * E_SZ];
    __shared__ short sB[E_SZ * E_SZ];
    __shared__ float red[2][128];

    const int tid = threadIdx.x;
    const int orig = blockIdx.x;
    const int nwg2 = P_SZ * 16;
    const int wgid = (orig & 7) * (nwg2 / 8) + (orig >> 3);
    const int p  = wgid >> 4;
    const int bb = wgid & 15;
    const int b0 = bb * 128;

    int fp = 0, rem = p;
    while (rem >= F_SZ - 1 - fp) { rem -= F_SZ - 1 - fp; ++fp; }
    const int fq = fp + 1 + rem;

#pragma unroll
    for (int k = 0; k < 4; ++k) {
        int i = tid + k * 512;
        int r = i >> 4, s8 = i & 15;
        const float* src = x + ((size_t)(b0 + r) * F_SZ + fp) * E_SZ + s8 * 8;
        float4 v0 = *(const float4*)src;
        float4 v1 = *(const float4*)(src + 4);
        bf16x8 h;
        h[0] = (__bf16)v0.x; h[1] = (__bf16)v0.y; h[2] = (__bf16)v0.z; h[3] = (__bf16)v0.w;
        h[4] = (__bf16)v1.x; h[5] = (__bf16)v1.y; h[6] = (__bf16)v1.z; h[7] = (__bf16)v1.w;
        *(bf16x8*)&sA[r * E_SZ + ((s8 ^ (r & 15)) << 3)] = h;
    }
#pragma unroll
    for (int k = 0; k < 4; ++k) {
        int i = tid + k * 512;
        int r = i >> 4, s8 = i & 15;
        const float* src = kern + ((size_t)r * P_SZ + p) * E_SZ + s8 * 8;
        float4 v0 = *(const float4*)src;
        float4 v1 = *(const float4*)(src + 4);
        bf16x8 h;
        h[0] = (__bf16)v0.x; h[1] = (__bf16)v0.y; h[2] = (__bf16)v0.z; h[3] = (__bf16)v0.w;
        h[4] = (__bf16)v1.x; h[5] = (__bf16)v1.y; h[6] = (__bf16)v1.z; h[7] = (__bf16)v1.w;
        *(bf16x8*)&sB[r * E_SZ + ((s8 ^ (r & 15)) << 3)] = h;
    }
    __syncthreads();

    const int w = tid >> 6, lane = tid & 63;
    const int l31 = lane & 31, hi = lane >> 5;
    const int mh = w >> 2, ng = w & 3;

    f32x16 acc[2];
#pragma unroll
    for (int mt = 0; mt < 2; ++mt)
#pragma unroll
        for (int j = 0; j < 16; ++j) acc[mt][j] = 0.f;

    const int brow = ng * 32 + l31;
#pragma unroll
    for (int kk = 0; kk < 8; ++kk) {
        const int e8 = kk * 2 + hi;
        bf16x8 bfr = *(const bf16x8*)&sA[brow * E_SZ + ((e8 ^ (brow & 15)) << 3)];
#pragma unroll
        for (int mt = 0; mt < 2; ++mt) {
            int arow = (mh * 2 + mt) * 32 + l31;
            bf16x8 afr = *(const bf16x8*)&sB[arow * E_SZ + ((e8 ^ (arow & 15)) << 3)];
            acc[mt] = __builtin_amdgcn_mfma_f32_32x32x16_bf16(afr, bfr, acc[mt], 0, 0, 0);
        }
    }

    const float* xqp = x + ((size_t)(b0 + brow) * F_SZ + fq) * E_SZ;
    float sv = 0.f;
#pragma unroll
    for (int mt = 0; mt < 2; ++mt) {
        const int dbase = (mh * 2 + mt) * 32 + hi * 4;
#pragma unroll
        for (int q = 0; q < 4; ++q) {
            float4 xq = *(const float4*)(xqp + dbase + q * 8);
            sv += acc[mt][q * 4 + 0] * xq.x + acc[mt][q * 4 + 1] * xq.y
                + acc[mt][q * 4 + 2] * xq.z + acc[mt][q * 4 + 3] * xq.w;
        }
    }
    sv += __shfl_xor(sv, 32);
    if (hi == 0) red[mh][brow] = sv;
    __syncthreads();

    if (tid < 128)
        out[(size_t)(b0 + tid) * P_SZ + p] = red[0][tid] + red[1][tid];
}

extern "C" void kernel_launch(void* const* d_in, const int* in_sizes, int n_in,
                              void* d_out, int out_size, void* d_ws, size_t ws_size,
                              hipStream_t stream) {
    const float* x    = (const float*)d_in[0];   // [2048, 24, 128] f32
    const float* kern = (const float*)d_in[1];   // [128, 276, 128] f32
    float* out = (float*)d_out;                  // [2048, 276] f32

    if (ws_size >= WS_NEED) {
        __bf16* xft = (__bf16*)d_ws;
        __bf16* xqt = xft + XT_ELEMS;
        __bf16* kb  = xqt + XT_ELEMS;
        prepack_all<<<dim3(XPREP_BLKS + KPREP_BLKS), 256, 0, stream>>>(x, kern, xft, xqt, kb);
        opn_main<<<dim3(NWG), 256, 0, stream>>>(xft, xqt, kb, out);
    } else {
        opn_fallback<<<dim3(P_SZ * 16), 512, 0, stream>>>(x, kern, out);
    }
}

// Round 8
// 45.586 us; speedup vs baseline: 1.4724x; 1.0199x over previous
//
#include <hip/hip_runtime.h>
#include <stdint.h>

#define B_SZ 2048
#define F_SZ 24
#define E_SZ 128
#define P_SZ 276            // F*(F-1)/2
#define BT   256            // batch rows per block (8 waves x 32 cols)
#define NWG  (P_SZ * 8)     // 2208 = 8 * 276 (one batch tile per XCD)

#define XT_ELEMS (B_SZ * F_SZ * E_SZ)   // 6,291,456 per x-transform (12.6 MB)
#define KB_ELEMS (P_SZ * E_SZ * E_SZ)   // 4,521,984 (9.0 MB)
#define WS_NEED  ((size_t)(2 * XT_ELEMS + KB_ELEMS) * 2)   // 34.2 MB

#define XPREP_BLKS (F_SZ * 64)          // 1536  (one per (f, 32-row group))
#define KPREP_BLKS (KB_ELEMS / 2048)    // 2208

typedef __bf16 bf16x8 __attribute__((ext_vector_type(8)));
typedef __bf16 bf16x4 __attribute__((ext_vector_type(4)));
typedef float  f32x16 __attribute__((ext_vector_type(16)));

// ---- prepack ----------------------------------------------------------------
// xft[f][grp<64][kk<8][lane<64][8]: lane=(hi*32+l31) holds
//   x[grp*32+l31][f][kk*16+hi*8+i]  -> MFMA B-frag loads are 1KB coalesced.
// xqt[f][grp<64][dq<32][bl<32][4]:  x[grp*32+bl][f][dq*4+i]
//   -> epilogue Xq loads are 2x256B coalesced dwordx2.
// kb[p][d][slot]: pre-XOR-swizzled K so a linear LDS DMA lands swizzled.
__global__ __launch_bounds__(256) void prepack_all(
    const float* __restrict__ x, const float* __restrict__ kern,
    __bf16* __restrict__ xft, __bf16* __restrict__ xqt, __bf16* __restrict__ kb)
{
    const int bid = blockIdx.x;
    const int tid = threadIdx.x;
    if (bid < XPREP_BLKS) {
        const int f = bid >> 6, grp = bid & 63;
        __shared__ float sT[32][129];       // +1 pad: conflict-free col reads
        {
            const int row = tid >> 3, c0 = (tid & 7) * 16;
            const float* src = x + ((size_t)(grp * 32 + row) * F_SZ + f) * E_SZ + c0;
            float4 v0 = ((const float4*)src)[0];
            float4 v1 = ((const float4*)src)[1];
            float4 v2 = ((const float4*)src)[2];
            float4 v3 = ((const float4*)src)[3];
            *(float4*)&sT[row][c0]      = v0;
            *(float4*)&sT[row][c0 + 4]  = v1;
            *(float4*)&sT[row][c0 + 8]  = v2;
            *(float4*)&sT[row][c0 + 12] = v3;
        }
        __syncthreads();
        {
            __bf16* dst = xft + ((size_t)(f * 64 + grp) * 8) * 512;
#pragma unroll
            for (int u = 0; u < 2; ++u) {
                const int slot = tid * 2 + u;
                const int kk = slot >> 6, lane = slot & 63;
                const int l31 = lane & 31, hi = lane >> 5;
                bf16x8 h;
#pragma unroll
                for (int i = 0; i < 8; ++i)
                    h[i] = (__bf16)sT[l31][kk * 16 + hi * 8 + i];
                *(bf16x8*)(dst + slot * 8) = h;
            }
        }
        {
            __bf16* dst = xqt + ((size_t)(f * 64 + grp) * 32) * 128;
#pragma unroll
            for (int u = 0; u < 4; ++u) {
                const int slot = tid * 4 + u;
                const int dq = slot >> 5, bl = slot & 31;
                bf16x4 h;
#pragma unroll
                for (int i = 0; i < 4; ++i)
                    h[i] = (__bf16)sT[bl][dq * 4 + i];
                *(bf16x4*)(dst + slot * 4) = h;
            }
        }
    } else {
        int g = (bid - XPREP_BLKS) * 256 + tid;   // 16B-slot id
        int p = g >> 11, r = g & 2047;
        int d = r >> 4, s = r & 15;
        const float* src = kern + ((size_t)d * P_SZ + p) * E_SZ + ((s ^ (d & 15)) << 3);
        float4 v0 = *(const float4*)src;
        float4 v1 = *(const float4*)(src + 4);
        bf16x8 h;
        h[0] = (__bf16)v0.x; h[1] = (__bf16)v0.y; h[2] = (__bf16)v0.z; h[3] = (__bf16)v0.w;
        h[4] = (__bf16)v1.x; h[5] = (__bf16)v1.y; h[6] = (__bf16)v1.z; h[7] = (__bf16)v1.w;
        *(bf16x8*)(kb + (size_t)g * 8) = h;
    }
}

// ---- main: one block = (pair p, 256-row batch tile). K_p (32 KB) is the ONLY
//      LDS/DMA traffic -- staged ONCE for 256 batch rows; Xp fragments and Xq
//      values load coalesced into registers. 8 waves, 2 blocks/CU.
__global__ __launch_bounds__(512, 2) void opn_main(
    const __bf16* __restrict__ xft, const __bf16* __restrict__ xqt,
    const __bf16* __restrict__ kb,  float* __restrict__ out)
{
    __shared__ short sK[E_SZ * E_SZ];   // 32 KB swizzled K_p

    const int tid = threadIdx.x, w = tid >> 6, lane = tid & 63;
    const int l31 = lane & 31, hi = lane >> 5;
    const int orig = blockIdx.x;
    // 8 same-pair blocks launch adjacently, one per XCD (K_p L3-hot);
    // each XCD's x working set = 256 rows (~3 MB xft+xqt), L2-resident.
    const int bb = orig & 7;            // batch tile = XCD
    const int p  = orig >> 3;           // 0..275

    int fp = 0, rem = p;
    while (rem >= F_SZ - 1 - fp) { rem -= F_SZ - 1 - fp; ++fp; }
    const int fq = fp + 1 + rem;

    // K_p DMA: linear copy of pre-swizzled image (4 x 1KB per wave)
    const __bf16* kp = kb + (size_t)p * (E_SZ * E_SZ);
#pragma unroll
    for (int t = 0; t < 4; ++t) {
        const int base = (w * 4 + t) * 64;
        __builtin_amdgcn_global_load_lds(
            (const __attribute__((address_space(1))) void*)(kp + (size_t)(base + lane) * 8),
            (__attribute__((address_space(3))) void*)(&sK[base * 8]),
            16, 0, 0);
    }

    const int grp = bb * 8 + w;         // this wave's 32-row batch group
    // Xp MFMA B-fragments: 8 coalesced dwordx4 into regs
    bf16x8 xpf[8];
    const __bf16* xpb = xft + ((size_t)(fp * 64 + grp) * 8) * 512 + lane * 8;
#pragma unroll
    for (int kk = 0; kk < 8; ++kk)
        xpf[kk] = *(const bf16x8*)(xpb + kk * 512);

    __syncthreads();                    // drains K DMA + joins waves

    // T[d,b] = K_p[d,e] . Xp[b,e]^T; wave owns all 128 d for its 32 b-cols
    f32x16 acc[4];
#pragma unroll
    for (int mt = 0; mt < 4; ++mt)
#pragma unroll
        for (int q = 0; q < 16; ++q) acc[mt][q] = 0.f;

#pragma unroll
    for (int kk = 0; kk < 8; ++kk) {
        const int e8 = kk * 2 + hi;
#pragma unroll
        for (int mt = 0; mt < 4; ++mt) {
            const int arow = mt * 32 + l31;
            bf16x8 afr = *(const bf16x8*)&sK[arow * E_SZ + ((e8 ^ (arow & 15)) << 3)];
            acc[mt] = __builtin_amdgcn_mfma_f32_32x32x16_bf16(afr, xpf[kk], acc[mt], 0, 0, 0);
        }
    }

    // Xq: 16 coalesced dwordx2 into regs (loaded AFTER MFMA to cut peak VGPR);
    // lane (l31,hi) gets Xq[b=grp*32+l31][d = mt*32 + q*8 + hi*4 + i]
    bf16x4 xqr[4][4];
    const __bf16* xqb = xqt + ((size_t)(fq * 64 + grp) * 32) * 128 + hi * 128 + l31 * 4;
#pragma unroll
    for (int mt = 0; mt < 4; ++mt)
#pragma unroll
        for (int q = 0; q < 4; ++q)
            xqr[mt][q] = *(const bf16x4*)(xqb + (size_t)(mt * 8 + q * 2) * 128);

    // epilogue: s = sum_d T[d,b] * Xq[b,d] -- all lane-local registers.
    // D layout: col = lane&31 (= b), row(d) = (reg&3) + 8*(reg>>2) + 4*hi
    float s = 0.f;
#pragma unroll
    for (int mt = 0; mt < 4; ++mt)
#pragma unroll
        for (int q = 0; q < 4; ++q)
            s += acc[mt][q * 4 + 0] * (float)xqr[mt][q][0]
               + acc[mt][q * 4 + 1] * (float)xqr[mt][q][1]
               + acc[mt][q * 4 + 2] * (float)xqr[mt][q][2]
               + acc[mt][q * 4 + 3] * (float)xqr[mt][q][3];
    s += __shfl_xor(s, 32);             // combine the two hi row-groups
    if (hi == 0)
        out[(size_t)(grp * 32 + l31) * P_SZ + p] = s;
}

// ---------------- fallback (round-2 kernel, used if ws too small) -----------
__global__ __launch_bounds__(512, 4) void opn_fallback(
    const float* __restrict__ x, const float* __restrict__ kern,
    float* __restrict__ out)
{
    __shared__ short sA[128 * E_SZ];
    __shared__ short sB[E_SZ * E_SZ];
    __shared__ float red[2][128];

    const int tid = threadIdx.x;
    const int orig = blockIdx.x;
    const int nwg2 = P_SZ * 16;
    const int wgid = (orig & 7) * (nwg2 / 8) + (orig >> 3);
    const int p  = wgid >> 4;
    const int bb = wgid & 15;
    const int b0 = bb * 128;

    int fp = 0, rem = p;
    while (rem >= F_SZ - 1 - fp) { rem -= F_SZ - 1 - fp; ++fp; }
    const int fq = fp + 1 + rem;

#pragma unroll
    for (int k = 0; k < 4; ++k) {
        int i = tid + k * 512;
        int r = i >> 4, s8 = i & 15;
        const float* src = x + ((size_t)(b0 + r) * F_SZ + fp) * E_SZ + s8 * 8;
        float4 v0 = *(const float4*)src;
        float4 v1 = *(const float4*)(src + 4);
        bf16x8 h;
        h[0] = (__bf16)v0.x; h[1] = (__bf16)v0.y; h[2] = (__bf16)v0.z; h[3] = (__bf16)v0.w;
        h[4] = (__bf16)v1.x; h[5] = (__bf16)v1.y; h[6] = (__bf16)v1.z; h[7] = (__bf16)v1.w;
        *(bf16x8*)&sA[r * E_SZ + ((s8 ^ (r & 15)) << 3)] = h;
    }
#pragma unroll
    for (int k = 0; k < 4; ++k) {
        int i = tid + k * 512;
        int r = i >> 4, s8 = i & 15;
        const float* src = kern + ((size_t)r * P_SZ + p) * E_SZ + s8 * 8;
        float4 v0 = *(const float4*)src;
        float4 v1 = *(const float4*)(src + 4);
        bf16x8 h;
        h[0] = (__bf16)v0.x; h[1] = (__bf16)v0.y; h[2] = (__bf16)v0.z; h[3] = (__bf16)v0.w;
        h[4] = (__bf16)v1.x; h[5] = (__bf16)v1.y; h[6] = (__bf16)v1.z; h[7] = (__bf16)v1.w;
        *(bf16x8*)&sB[r * E_SZ + ((s8 ^ (r & 15)) << 3)] = h;
    }
    __syncthreads();

    const int w = tid >> 6, lane = tid & 63;
    const int l31 = lane & 31, hi = lane >> 5;
    const int mh = w >> 2, ng = w & 3;

    f32x16 acc[2];
#pragma unroll
    for (int mt = 0; mt < 2; ++mt)
#pragma unroll
        for (int j = 0; j < 16; ++j) acc[mt][j] = 0.f;

    const int brow = ng * 32 + l31;
#pragma unroll
    for (int kk = 0; kk < 8; ++kk) {
        const int e8 = kk * 2 + hi;
        bf16x8 bfr = *(const bf16x8*)&sA[brow * E_SZ + ((e8 ^ (brow & 15)) << 3)];
#pragma unroll
        for (int mt = 0; mt < 2; ++mt) {
            int arow = (mh * 2 + mt) * 32 + l31;
            bf16x8 afr = *(const bf16x8*)&sB[arow * E_SZ + ((e8 ^ (arow & 15)) << 3)];
            acc[mt] = __builtin_amdgcn_mfma_f32_32x32x16_bf16(afr, bfr, acc[mt], 0, 0, 0);
        }
    }

    const float* xqp = x + ((size_t)(b0 + brow) * F_SZ + fq) * E_SZ;
    float sv = 0.f;
#pragma unroll
    for (int mt = 0; mt < 2; ++mt) {
        const int dbase = (mh * 2 + mt) * 32 + hi * 4;
#pragma unroll
        for (int q = 0; q < 4; ++q) {
            float4 xq = *(const float4*)(xqp + dbase + q * 8);
            sv += acc[mt][q * 4 + 0] * xq.x + acc[mt][q * 4 + 1] * xq.y
                + acc[mt][q * 4 + 2] * xq.z + acc[mt][q * 4 + 3] * xq.w;
        }
    }
    sv += __shfl_xor(sv, 32);
    if (hi == 0) red[mh][brow] = sv;
    __syncthreads();

    if (tid < 128)
        out[(size_t)(b0 + tid) * P_SZ + p] = red[0][tid] + red[1][tid];
}

extern "C" void kernel_launch(void* const* d_in, const int* in_sizes, int n_in,
                              void* d_out, int out_size, void* d_ws, size_t ws_size,
                              hipStream_t stream) {
    const float* x    = (const float*)d_in[0];   // [2048, 24, 128] f32
    const float* kern = (const float*)d_in[1];   // [128, 276, 128] f32
    float* out = (float*)d_out;                  // [2048, 276] f32

    if (ws_size >= WS_NEED) {
        __bf16* xft = (__bf16*)d_ws;
        __bf16* xqt = xft + XT_ELEMS;
        __bf16* kb  = xqt + XT_ELEMS;
        prepack_all<<<dim3(XPREP_BLKS + KPREP_BLKS), 256, 0, stream>>>(x, kern, xft, xqt, kb);
        opn_main<<<dim3(NWG), 512, 0, stream>>>(xft, xqt, kb, out);
    } else {
        opn_fallback<<<dim3(P_SZ * 16), 512, 0, stream>>>(x, kern, out);
    }
}